// Round 7
// baseline (175.206 us; speedup 1.0000x reference)
//
#include <hip/hip_runtime.h>
#include <hip/hip_bf16.h>
#include <stdint.h>

#define BATCH 256
#define PFD 128
#define T1 129
#define NPAIRS 1089      // 33*33
#define BH 72            // b_lds row stride (shorts): 64 k + 8 pad; 36 dw -> 2-way b128 reads
#define CHUNK 8

typedef short bf16x8 __attribute__((ext_vector_type(8)));
typedef float f32x4 __attribute__((ext_vector_type(4)));

static __device__ __forceinline__ float float_of(unsigned u){ union{float f;unsigned u;}x;x.u=u;return x.f; }
static __device__ __forceinline__ unsigned pk_bf16(float a, float b){
  union { __hip_bfloat162 h; unsigned u; } c;
  c.h = __float22bfloat162_rn(make_float2(a, b));
  return c.u;
}

// ---------------- Kernel 1: split-K fused trilinear GEMM ----------------
// TLP version. Round 3-6 lesson: with one resident 512-thread block/CU
// (192 unified regs/wave), every barrier stalls the whole CU and no
// source-level pipelining recovers it (counted-vmcnt attempts spilled or
// drained). Fix: HALVE the block (256 thr / 4 waves, m-half 128 x n 128,
// LDS 41 KB, ~190 regs) so TWO independent blocks co-reside per CU
// (guaranteed: 82 KB LDS < 160, 8 waves/CU at <=256 regs). Their barriers
// are independent -> one block's staging stall hides under the other's
// compute. Per-wave tile, layouts, and numerics identical to the verified
// round-3 kernel; part layout unchanged (m-halves write disjoint rows).
// Pipeline per half-pair s: stage(pf -> buf s&1); __syncthreads (free
// drain: pf was consumed, loads issued last step already landed);
// issue pf loads for s+1 AFTER the barrier (full compute phase to land);
// compute. Buffer reuse safe: reads of buf X at step s are issued before
// that wave's stage(s+1) ds_writes (per-wave LDS order), and the next
// write to buf X is stage(s+2), gated behind barrier(s+1).
__global__ __launch_bounds__(256, 2) void tfn_k1(
    const float* __restrict__ audio, const float* __restrict__ video,
    const float* __restrict__ text, const float* __restrict__ W1,
    unsigned short* __restrict__ part, int S) {
  __shared__ __align__(16) short b_lds[2][PFD * BH];    // 2 x 18432 B, [n][k_local]
  __shared__ __align__(16) float av_lds[128 * CHUNK];   // 4 KB (m-half local)

  const int tid = threadIdx.x;
  const int bk = blockIdx.x;
  const int sidx = bk % S;        // pair-set index (part slab)
  const int mh = bk / S;          // m-half: 0 -> rows 0..127, 1 -> 128..255
  const int npb = NPAIRS / S, rem0 = NPAIRS % S;
  const int p0 = sidx * npb + (sidx < rem0 ? sidx : rem0);
  const int np = npb + (sidx < rem0 ? 1 : 0);

  const int wave = tid >> 6, lane = tid & 63;           // wave in [0,4)
  const int l15 = lane & 15, quad = lane >> 4;
  const int sn = tid & 127, skg = tid >> 7;             // staging: n col, k group

  // t fragments, fp32, MFMA A-layout: treg[mt][ks*8+j] = t(m, ks*32+quad*8+j)
  // wave covers m_local = wave*32 + mt*16 + l15  (4 waves x 32 = 128 rows)
  float treg[2][32];
  float t128r[2];
  #pragma unroll
  for (int mt = 0; mt < 2; ++mt) {
    const int m = mh * 128 + wave * 32 + mt * 16 + l15;
    t128r[mt] = text[m * 128 + 127];
    #pragma unroll
    for (int ks = 0; ks < 4; ++ks)
      #pragma unroll
      for (int j = 0; j < 8; ++j) {
        const int it = ks * 32 + quad * 8 + j;
        treg[mt][ks * 8 + j] = (it == 0) ? 1.0f : text[m * 128 + it - 1];
      }
  }

  f32x4 acc[2][8];
  #pragma unroll
  for (int a = 0; a < 2; ++a)
    #pragma unroll
    for (int b = 0; b < 8; ++b) acc[a][b] = f32x4{0.f, 0.f, 0.f, 0.f};

  float pf[32], rv[8];

  for (int c0 = 0; c0 < np; c0 += CHUNK) {
    const int nc = (np - c0) < CHUNK ? (np - c0) : CHUNK;
    const int pbase = p0 + c0;
    __syncthreads();   // prev chunk fully done
    if (tid < 128) {
      const int ml = tid;
      const int m = mh * 128 + ml;
      for (int j = 0; j < nc; ++j) {
        int p = pbase + j;
        int ia = p / 33, iv = p - ia * 33;
        float a = (ia == 0) ? 1.0f : audio[m * 32 + ia - 1];
        float v = (iv == 0) ? 1.0f : video[m * 32 + iv - 1];
        av_lds[ml * CHUNK + j] = a * v;
      }
    }
    // remainder row (it=128) — oldest in-flight loads, drained at first barrier
    #pragma unroll
    for (int j = 0; j < 8; ++j) {
      int kk = skg * 8 + j;
      rv[j] = (kk < nc) ? W1[((long)(pbase + kk) * T1 + 128) * PFD + sn] : 0.0f;
    }

    // pf covers one HALF-pair (64 k-rows x 128 n): row = h*64 + g*16 + skg*8 + j
    auto load_pf = [&](int s) {
      const long rb = (long)(pbase + (s >> 1)) * T1 + (s & 1) * 64;
      #pragma unroll
      for (int g = 0; g < 4; ++g)
        #pragma unroll
        for (int j = 0; j < 8; ++j)
          pf[g * 8 + j] = W1[(rb + g * 16 + skg * 8 + j) * PFD + sn];
    };

    load_pf(0);   // prime (latency exposed once per chunk only)

    const int NS = 2 * nc;
    for (int s = 0; s < NS; ++s) {
      const int buf = s & 1;
      // ---- stage half-pair s: pf -> b_lds[buf] [n][k_local 0..63] ----
      {
        union { bf16x8 v; unsigned u[4]; } w;
        #pragma unroll
        for (int g = 0; g < 4; ++g) {
          #pragma unroll
          for (int d = 0; d < 4; ++d)
            w.u[d] = pk_bf16(pf[g * 8 + 2 * d], pf[g * 8 + 2 * d + 1]);
          *(bf16x8*)&b_lds[buf][sn * BH + g * 16 + skg * 8] = w.v;
        }
      }
      __syncthreads();   // staged; vmcnt drain free (pf consumed, older loads landed)
      // ---- issue next half-pair's loads (full compute phase to land) ----
      if (s + 1 < NS) load_pf(s + 1);
      // ---- compute half-pair s ----
      {
        const int sp = s >> 1, h = s & 1;
        const float avm0 = av_lds[(wave * 32 + l15) * CHUNK + sp];
        const float avm1 = av_lds[(wave * 32 + 16 + l15) * CHUNK + sp];
        #pragma unroll
        for (int ksl = 0; ksl < 2; ++ksl) {
          const int ks = h * 2 + ksl;
          bf16x8 A0, A1;
          {
            union { bf16x8 v; unsigned u[4]; } c0u, c1u;
            #pragma unroll
            for (int d = 0; d < 4; ++d) {
              c0u.u[d] = pk_bf16(avm0 * treg[0][ks * 8 + 2 * d], avm0 * treg[0][ks * 8 + 2 * d + 1]);
              c1u.u[d] = pk_bf16(avm1 * treg[1][ks * 8 + 2 * d], avm1 * treg[1][ks * 8 + 2 * d + 1]);
            }
            A0 = c0u.v; A1 = c1u.v;
          }
          #pragma unroll
          for (int nt = 0; nt < 8; ++nt) {
            bf16x8 bf = *(const bf16x8*)&b_lds[buf][(nt * 16 + l15) * BH + ksl * 32 + quad * 8];
            acc[0][nt] = __builtin_amdgcn_mfma_f32_16x16x32_bf16(A0, bf, acc[0][nt], 0, 0, 0);
            acc[1][nt] = __builtin_amdgcn_mfma_f32_16x16x32_bf16(A1, bf, acc[1][nt], 0, 0, 0);
          }
        }
      }
    }

    // ---- remainder tile: it=128, k-slot = pair index within chunk ----
    __syncthreads();   // all compute done; b_lds[0] reusable
    {
      union { bf16x8 v; unsigned u[4]; } w;
      #pragma unroll
      for (int d = 0; d < 4; ++d) w.u[d] = pk_bf16(rv[2 * d], rv[2 * d + 1]);
      *(bf16x8*)&b_lds[0][sn * BH + skg * 8] = w.v;
    }
    __syncthreads();
    {
      bf16x8 A[2];
      #pragma unroll
      for (int mt = 0; mt < 2; ++mt) {
        const int ml = wave * 32 + mt * 16 + l15;
        union { bf16x8 v; unsigned u[4]; } c;
        #pragma unroll
        for (int d = 0; d < 4; ++d) {
          int k0 = quad * 8 + 2 * d, k1 = k0 + 1;
          float f0 = (k0 < nc) ? av_lds[ml * CHUNK + k0] * t128r[mt] : 0.0f;
          float f1 = (k1 < nc) ? av_lds[ml * CHUNK + k1] * t128r[mt] : 0.0f;
          c.u[d] = pk_bf16(f0, f1);
        }
        A[mt] = c.v;
      }
      #pragma unroll
      for (int nt = 0; nt < 8; ++nt) {
        bf16x8 bf = *(const bf16x8*)&b_lds[0][(nt * 16 + l15) * BH + quad * 8];
        acc[0][nt] = __builtin_amdgcn_mfma_f32_16x16x32_bf16(A[0], bf, acc[0][nt], 0, 0, 0);
        acc[1][nt] = __builtin_amdgcn_mfma_f32_16x16x32_bf16(A[1], bf, acc[1][nt], 0, 0, 0);
      }
    }
  }

  // writeback: bf16, m-major [m][S][phys_n], phys n = l15*8 + nt
  #pragma unroll
  for (int mt = 0; mt < 2; ++mt)
    #pragma unroll
    for (int r = 0; r < 4; ++r) {
      const int m = mh * 128 + wave * 32 + mt * 16 + quad * 4 + r;
      union { bf16x8 v; unsigned u[4]; } w;
      #pragma unroll
      for (int d = 0; d < 4; ++d) w.u[d] = pk_bf16(acc[mt][2 * d][r], acc[mt][2 * d + 1][r]);
      *(bf16x8*)&part[((size_t)m * S + sidx) * PFD + l15 * 8] = w.v;
    }
}

// ---------------- Kernel 2: contiguous reduce + bias/relu + layers 2,3 ----------------
__global__ __launch_bounds__(1024) void tfn_k2(
    const unsigned short* __restrict__ part, const float* __restrict__ b1,
    const float* __restrict__ W2, const float* __restrict__ b2,
    const float* __restrict__ W3, const float* __restrict__ b3,
    float* __restrict__ out, int S) {
  __shared__ float sred[1024 * 4];   // 16 KB
  __shared__ float h1s[PFD];
  __shared__ float a2s[1024];
  __shared__ float red[2];
  const int m = blockIdx.x, tid = threadIdx.x;
  const int g = tid & 31, q = tid >> 5;       // 32 s-groups of 32 slabs
  const unsigned short* base = part + (size_t)m * S * PFD;
  float s0 = 0, s1 = 0, s2 = 0, s3 = 0;
  for (int bkk = q; bkk < S; bkk += 32) {
    uint2 v = *(const uint2*)&base[(size_t)bkk * PFD + g * 4];
    s0 += float_of(v.x << 16);
    s1 += float_of(v.x & 0xFFFF0000u);
    s2 += float_of(v.y << 16);
    s3 += float_of(v.y & 0xFFFF0000u);
  }
  sred[tid * 4 + 0] = s0; sred[tid * 4 + 1] = s1;
  sred[tid * 4 + 2] = s2; sred[tid * 4 + 3] = s3;
  __syncthreads();
  if (tid < PFD) {
    const int p = tid;
    float h = 0;
    #pragma unroll
    for (int bl = 0; bl < 32; ++bl) h += sred[(bl * 32 + (p >> 2)) * 4 + (p & 3)];
    const int n = (p & 7) * 16 + (p >> 3);   // un-swizzle phys -> logical
    h1s[n] = fmaxf(h + b1[n], 0.0f);
  }
  __syncthreads();
  const int n = tid & 127, kq = tid >> 7;    // 8 k-groups of 16
  float a2 = 0.0f;
  const int k0 = kq * 16;
  #pragma unroll
  for (int k = 0; k < 16; ++k) a2 += h1s[k0 + k] * W2[(k0 + k) * PFD + n];
  a2s[tid] = a2;
  __syncthreads();
  if (tid < 128) {
    float h2 = 0.0f;
    #pragma unroll
    for (int j = 0; j < 8; ++j) h2 += a2s[n + 128 * j];
    h2 = fmaxf(h2 + b2[n], 0.0f);
    float pr = h2 * W3[n];
    #pragma unroll
    for (int off = 32; off > 0; off >>= 1) pr += __shfl_down(pr, off);
    if ((tid & 63) == 0) red[tid >> 6] = pr;
  }
  __syncthreads();
  if (tid == 0) out[m] = red[0] + red[1] + b3[0];
}

extern "C" void kernel_launch(void* const* d_in, const int* in_sizes, int n_in,
                              void* d_out, int out_size, void* d_ws, size_t ws_size,
                              hipStream_t stream) {
  const float* audio = (const float*)d_in[0];
  const float* video = (const float*)d_in[1];
  const float* text  = (const float*)d_in[2];
  const float* W1 = (const float*)d_in[3];
  const float* b1 = (const float*)d_in[4];
  const float* W2 = (const float*)d_in[5];
  const float* b2 = (const float*)d_in[6];
  const float* W3 = (const float*)d_in[7];
  const float* b3 = (const float*)d_in[8];
  unsigned short* part = (unsigned short*)d_ws;

  const size_t slab = (size_t)BATCH * PFD * sizeof(unsigned short);  // 64 KB
  int S = (int)(ws_size / slab);
  if (S > 256) S = 256;
  if (S < 1) S = 1;

  tfn_k1<<<2 * S, 256, 0, stream>>>(audio, video, text, W1, part, S);
  tfn_k2<<<BATCH, 1024, 0, stream>>>(part, b1, W2, b2, W3, b3, (float*)d_out, S);
}

// Round 8
// 174.729 us; speedup vs baseline: 1.0027x; 1.0027x over previous
//
#include <hip/hip_runtime.h>
#include <hip/hip_bf16.h>
#include <stdint.h>

#define BATCH 256
#define PFD 128
#define T1 129
#define NPAIRS 1089      // 33*33
#define BH 72            // b_lds row stride (shorts): 64 k + 8 pad
#define CHUNK 8

typedef short bf16x8 __attribute__((ext_vector_type(8)));
typedef float f32x4 __attribute__((ext_vector_type(4)));

static __device__ __forceinline__ float float_of(unsigned u){ union{float f;unsigned u;}x;x.u=u;return x.f; }
static __device__ __forceinline__ unsigned pk_bf16(float a, float b){
  union { __hip_bfloat162 h; unsigned u; } c;
  c.h = __float22bfloat162_rn(make_float2(a, b));
  return c.u;
}

// ---------------- Kernel 1: split-K fused trilinear GEMM ----------------
// TLP version, allocator-friendly. Round-7 failure analysis: the code was
// right but __launch_bounds__(256,2) made the allocator clamp to 80 VGPRs
// and spill ~33MB of scratch (same failure as rounds 1/6 — every explicit
// occupancy hint clamped; plain (512,2)/straight-line code allocated 128+64
// cleanly). Here: __launch_bounds__(256) with NO min-wave arg, lambdas
// inlined to straight-line code (round-3 codegen shape). At the natural
// ~192 unified regs/wave a 4-wave block gives 2 waves/SIMD -> TWO blocks/CU
// from hardware arithmetic, no hint needed. Twin blocks bk and bk+S (same
// pair-set, other m-half) land on the same CU and march the same W1 slabs
// in lockstep -> second read hits L2/L3.
// Pipeline per half-pair s: stage(pf -> buf s&1); __syncthreads (free
// drain: pf consumed, last step's loads landed); issue next pf loads AFTER
// the barrier (full compute phase to land); compute. Buffer reuse safe:
// reads of buf X at step s are issued before that wave's stage(s+1)
// ds_writes; next write to buf X is stage(s+2), gated behind barrier(s+1).
__global__ __launch_bounds__(256) void tfn_k1(
    const float* __restrict__ audio, const float* __restrict__ video,
    const float* __restrict__ text, const float* __restrict__ W1,
    unsigned short* __restrict__ part, int S) {
  __shared__ __align__(16) short b_lds[2][PFD * BH];    // 2 x 18432 B, [n][k_local]
  __shared__ __align__(16) float av_lds[128 * CHUNK];   // 4 KB (m-half local)

  const int tid = threadIdx.x;
  const int bk = blockIdx.x;
  const int sidx = bk % S;        // pair-set index (part slab)
  const int mh = bk / S;          // m-half: 0 -> rows 0..127, 1 -> 128..255
  const int npb = NPAIRS / S, rem0 = NPAIRS % S;
  const int p0 = sidx * npb + (sidx < rem0 ? sidx : rem0);
  const int np = npb + (sidx < rem0 ? 1 : 0);

  const int wave = tid >> 6, lane = tid & 63;           // wave in [0,4)
  const int l15 = lane & 15, quad = lane >> 4;
  const int sn = tid & 127, skg = tid >> 7;             // staging: n col, k group

  // t fragments, fp32, MFMA A-layout: treg[mt][ks*8+j] = t(m, ks*32+quad*8+j)
  float treg[2][32];
  float t128r[2];
  #pragma unroll
  for (int mt = 0; mt < 2; ++mt) {
    const int m = mh * 128 + wave * 32 + mt * 16 + l15;
    t128r[mt] = text[m * 128 + 127];
    #pragma unroll
    for (int ks = 0; ks < 4; ++ks)
      #pragma unroll
      for (int j = 0; j < 8; ++j) {
        const int it = ks * 32 + quad * 8 + j;
        treg[mt][ks * 8 + j] = (it == 0) ? 1.0f : text[m * 128 + it - 1];
      }
  }

  f32x4 acc[2][8];
  #pragma unroll
  for (int a = 0; a < 2; ++a)
    #pragma unroll
    for (int b = 0; b < 8; ++b) acc[a][b] = f32x4{0.f, 0.f, 0.f, 0.f};

  float pf[32], rv[8];

  for (int c0 = 0; c0 < np; c0 += CHUNK) {
    const int nc = (np - c0) < CHUNK ? (np - c0) : CHUNK;
    const int pbase = p0 + c0;
    __syncthreads();   // prev chunk fully done
    if (tid < 128) {
      const int ml = tid;
      const int m = mh * 128 + ml;
      for (int j = 0; j < nc; ++j) {
        int p = pbase + j;
        int ia = p / 33, iv = p - ia * 33;
        float a = (ia == 0) ? 1.0f : audio[m * 32 + ia - 1];
        float v = (iv == 0) ? 1.0f : video[m * 32 + iv - 1];
        av_lds[ml * CHUNK + j] = a * v;
      }
    }
    // remainder row (it=128) — oldest in-flight loads, drained at first barrier
    #pragma unroll
    for (int j = 0; j < 8; ++j) {
      int kk = skg * 8 + j;
      rv[j] = (kk < nc) ? W1[((long)(pbase + kk) * T1 + 128) * PFD + sn] : 0.0f;
    }

    // prime: half-pair 0 (rows g*16+skg*8+j of pair 0's first k-half)
    {
      const long rb = (long)pbase * T1;
      #pragma unroll
      for (int g = 0; g < 4; ++g)
        #pragma unroll
        for (int j = 0; j < 8; ++j)
          pf[g * 8 + j] = W1[(rb + g * 16 + skg * 8 + j) * PFD + sn];
    }

    const int NS = 2 * nc;
    for (int s = 0; s < NS; ++s) {
      const int buf = s & 1;
      // ---- stage half-pair s: pf -> b_lds[buf] [n][k_local 0..63] ----
      {
        union { bf16x8 v; unsigned u[4]; } w;
        #pragma unroll
        for (int g = 0; g < 4; ++g) {
          #pragma unroll
          for (int d = 0; d < 4; ++d)
            w.u[d] = pk_bf16(pf[g * 8 + 2 * d], pf[g * 8 + 2 * d + 1]);
          *(bf16x8*)&b_lds[buf][sn * BH + g * 16 + skg * 8] = w.v;
        }
      }
      __syncthreads();   // staged; vmcnt drain free (pf consumed, older loads landed)
      // ---- issue next half-pair's loads (full compute phase to land) ----
      if (s + 1 < NS) {
        const long rb = (long)(pbase + ((s + 1) >> 1)) * T1 + ((s + 1) & 1) * 64;
        #pragma unroll
        for (int g = 0; g < 4; ++g)
          #pragma unroll
          for (int j = 0; j < 8; ++j)
            pf[g * 8 + j] = W1[(rb + g * 16 + skg * 8 + j) * PFD + sn];
      }
      // ---- compute half-pair s ----
      {
        const int sp = s >> 1, h = s & 1;
        const float avm0 = av_lds[(wave * 32 + l15) * CHUNK + sp];
        const float avm1 = av_lds[(wave * 32 + 16 + l15) * CHUNK + sp];
        #pragma unroll
        for (int ksl = 0; ksl < 2; ++ksl) {
          const int ks = h * 2 + ksl;
          bf16x8 A0, A1;
          {
            union { bf16x8 v; unsigned u[4]; } c0u, c1u;
            #pragma unroll
            for (int d = 0; d < 4; ++d) {
              c0u.u[d] = pk_bf16(avm0 * treg[0][ks * 8 + 2 * d], avm0 * treg[0][ks * 8 + 2 * d + 1]);
              c1u.u[d] = pk_bf16(avm1 * treg[1][ks * 8 + 2 * d], avm1 * treg[1][ks * 8 + 2 * d + 1]);
            }
            A0 = c0u.v; A1 = c1u.v;
          }
          #pragma unroll
          for (int nt = 0; nt < 8; ++nt) {
            bf16x8 bf = *(const bf16x8*)&b_lds[buf][(nt * 16 + l15) * BH + ksl * 32 + quad * 8];
            acc[0][nt] = __builtin_amdgcn_mfma_f32_16x16x32_bf16(A0, bf, acc[0][nt], 0, 0, 0);
            acc[1][nt] = __builtin_amdgcn_mfma_f32_16x16x32_bf16(A1, bf, acc[1][nt], 0, 0, 0);
          }
        }
      }
    }

    // ---- remainder tile: it=128, k-slot = pair index within chunk ----
    __syncthreads();   // all compute done; b_lds[0] reusable
    {
      union { bf16x8 v; unsigned u[4]; } w;
      #pragma unroll
      for (int d = 0; d < 4; ++d) w.u[d] = pk_bf16(rv[2 * d], rv[2 * d + 1]);
      *(bf16x8*)&b_lds[0][sn * BH + skg * 8] = w.v;
    }
    __syncthreads();
    {
      bf16x8 A[2];
      #pragma unroll
      for (int mt = 0; mt < 2; ++mt) {
        const int ml = wave * 32 + mt * 16 + l15;
        union { bf16x8 v; unsigned u[4]; } c;
        #pragma unroll
        for (int d = 0; d < 4; ++d) {
          int k0 = quad * 8 + 2 * d, k1 = k0 + 1;
          float f0 = (k0 < nc) ? av_lds[ml * CHUNK + k0] * t128r[mt] : 0.0f;
          float f1 = (k1 < nc) ? av_lds[ml * CHUNK + k1] * t128r[mt] : 0.0f;
          c.u[d] = pk_bf16(f0, f1);
        }
        A[mt] = c.v;
      }
      #pragma unroll
      for (int nt = 0; nt < 8; ++nt) {
        bf16x8 bf = *(const bf16x8*)&b_lds[0][(nt * 16 + l15) * BH + quad * 8];
        acc[0][nt] = __builtin_amdgcn_mfma_f32_16x16x32_bf16(A[0], bf, acc[0][nt], 0, 0, 0);
        acc[1][nt] = __builtin_amdgcn_mfma_f32_16x16x32_bf16(A[1], bf, acc[1][nt], 0, 0, 0);
      }
    }
  }

  // writeback: bf16, m-major [m][S][phys_n], phys n = l15*8 + nt
  #pragma unroll
  for (int mt = 0; mt < 2; ++mt)
    #pragma unroll
    for (int r = 0; r < 4; ++r) {
      const int m = mh * 128 + wave * 32 + mt * 16 + quad * 4 + r;
      union { bf16x8 v; unsigned u[4]; } w;
      #pragma unroll
      for (int d = 0; d < 4; ++d) w.u[d] = pk_bf16(acc[mt][2 * d][r], acc[mt][2 * d + 1][r]);
      *(bf16x8*)&part[((size_t)m * S + sidx) * PFD + l15 * 8] = w.v;
    }
}

// ---------------- Kernel 2: contiguous reduce + bias/relu + layers 2,3 ----------------
__global__ __launch_bounds__(1024) void tfn_k2(
    const unsigned short* __restrict__ part, const float* __restrict__ b1,
    const float* __restrict__ W2, const float* __restrict__ b2,
    const float* __restrict__ W3, const float* __restrict__ b3,
    float* __restrict__ out, int S) {
  __shared__ float sred[1024 * 4];   // 16 KB
  __shared__ float h1s[PFD];
  __shared__ float a2s[1024];
  __shared__ float red[2];
  const int m = blockIdx.x, tid = threadIdx.x;
  const int g = tid & 31, q = tid >> 5;       // 32 s-groups of 32 slabs
  const unsigned short* base = part + (size_t)m * S * PFD;
  float s0 = 0, s1 = 0, s2 = 0, s3 = 0;
  for (int bkk = q; bkk < S; bkk += 32) {
    uint2 v = *(const uint2*)&base[(size_t)bkk * PFD + g * 4];
    s0 += float_of(v.x << 16);
    s1 += float_of(v.x & 0xFFFF0000u);
    s2 += float_of(v.y << 16);
    s3 += float_of(v.y & 0xFFFF0000u);
  }
  sred[tid * 4 + 0] = s0; sred[tid * 4 + 1] = s1;
  sred[tid * 4 + 2] = s2; sred[tid * 4 + 3] = s3;
  __syncthreads();
  if (tid < PFD) {
    const int p = tid;
    float h = 0;
    #pragma unroll
    for (int bl = 0; bl < 32; ++bl) h += sred[(bl * 32 + (p >> 2)) * 4 + (p & 3)];
    const int n = (p & 7) * 16 + (p >> 3);   // un-swizzle phys -> logical
    h1s[n] = fmaxf(h + b1[n], 0.0f);
  }
  __syncthreads();
  const int n = tid & 127, kq = tid >> 7;    // 8 k-groups of 16
  float a2 = 0.0f;
  const int k0 = kq * 16;
  #pragma unroll
  for (int k = 0; k < 16; ++k) a2 += h1s[k0 + k] * W2[(k0 + k) * PFD + n];
  a2s[tid] = a2;
  __syncthreads();
  if (tid < 128) {
    float h2 = 0.0f;
    #pragma unroll
    for (int j = 0; j < 8; ++j) h2 += a2s[n + 128 * j];
    h2 = fmaxf(h2 + b2[n], 0.0f);
    float pr = h2 * W3[n];
    #pragma unroll
    for (int off = 32; off > 0; off >>= 1) pr += __shfl_down(pr, off);
    if ((tid & 63) == 0) red[tid >> 6] = pr;
  }
  __syncthreads();
  if (tid == 0) out[m] = red[0] + red[1] + b3[0];
}

extern "C" void kernel_launch(void* const* d_in, const int* in_sizes, int n_in,
                              void* d_out, int out_size, void* d_ws, size_t ws_size,
                              hipStream_t stream) {
  const float* audio = (const float*)d_in[0];
  const float* video = (const float*)d_in[1];
  const float* text  = (const float*)d_in[2];
  const float* W1 = (const float*)d_in[3];
  const float* b1 = (const float*)d_in[4];
  const float* W2 = (const float*)d_in[5];
  const float* b2 = (const float*)d_in[6];
  const float* W3 = (const float*)d_in[7];
  const float* b3 = (const float*)d_in[8];
  unsigned short* part = (unsigned short*)d_ws;

  const size_t slab = (size_t)BATCH * PFD * sizeof(unsigned short);  // 64 KB
  int S = (int)(ws_size / slab);
  if (S > 256) S = 256;
  if (S < 1) S = 1;

  tfn_k1<<<2 * S, 256, 0, stream>>>(audio, video, text, W1, part, S);
  tfn_k2<<<BATCH, 1024, 0, stream>>>(part, b1, W2, b2, W3, b3, (float*)d_out, S);
}

// Round 9
// 146.594 us; speedup vs baseline: 1.1952x; 1.1919x over previous
//
#include <hip/hip_runtime.h>
#include <hip/hip_bf16.h>
#include <stdint.h>

#define BATCH 256
#define PFD 128
#define T1 129
#define NPAIRS 1089      // 33*33
#define BK2 136          // b_lds row stride (shorts): 128 k + 8 pad
#define CHUNK 8

typedef short bf16x8 __attribute__((ext_vector_type(8)));
typedef float f32x4 __attribute__((ext_vector_type(4)));

static __device__ __forceinline__ float float_of(unsigned u){ union{float f;unsigned u;}x;x.u=u;return x.f; }
static __device__ __forceinline__ unsigned pk_bf16(float a, float b){
  union { __hip_bfloat162 h; unsigned u; } c;
  c.h = __float22bfloat162_rn(make_float2(a, b));
  return c.u;
}

// ---------------- Kernel 1: split-K fused trilinear GEMM ----------------
// Round-3 verified base (512 thr, (512,2), plain __syncthreads, straight-line
// code -> 128+64 regs no spill, k1=37us) + DEPTH-2 register prefetch.
// Cadence analysis of round 3: per pair the CU streams 66KB of W1 at ~10B/cyc
// fair-share (~6.5K cyc) but depth-1 prefetch covers it with only the ~2.5K-cyc
// compute phase -> ~4K-cyc vmcnt stall at every staging. Depth-2 (pfA/pfB,
// pair p+2 issued after barrier p) gives ~2 compute + 1 staging phase of cover.
// NOTE toolchain constraints learned rounds 1,4,6,7,8: no 256-thread blocks
// (allocator clamps to 80 VGPR + spills, regardless of launch bounds), no
// inline-asm waitcnt (forces conservative drains or spills), no sched_barrier
// walls, no clamped/branchless redundant loads. Plain C only.
// Race safety (per round-3 proof): one barrier per pair, stage(p) writes
// buf[p&1]; compute(p) reads it after sync(p); next write is stage(p+2),
// which every wave executes only after sync(p+1); __syncthreads' lgkmcnt(0)
// guarantees all compute(p) ds_reads retired before any wave passes sync(p+1).
__global__ __launch_bounds__(512, 2) void tfn_k1(
    const float* __restrict__ audio, const float* __restrict__ video,
    const float* __restrict__ text, const float* __restrict__ W1,
    unsigned short* __restrict__ part, int S) {
  __shared__ __align__(16) short b_lds[2][PFD * BK2];   // 2 x 34816 B
  __shared__ __align__(16) float av_lds[BATCH * CHUNK]; // 8192 B

  const int tid = threadIdx.x;
  const int bk = blockIdx.x;
  const int npb = NPAIRS / S, rem0 = NPAIRS % S;
  const int p0 = bk * npb + (bk < rem0 ? bk : rem0);
  const int np = npb + (bk < rem0 ? 1 : 0);

  const int wave = tid >> 6, lane = tid & 63;
  const int l15 = lane & 15, quad = lane >> 4;
  const int sn = tid & 127, skg = tid >> 7;

  // t fragments in registers, fp32, MFMA A-layout: treg[mt][ks*8+j] = t(m, ks*32+quad*8+j)
  float treg[2][32];
  float t128r[2];
  #pragma unroll
  for (int mt = 0; mt < 2; ++mt) {
    const int m = wave * 32 + mt * 16 + l15;
    t128r[mt] = text[m * 128 + 127];
    #pragma unroll
    for (int ks = 0; ks < 4; ++ks)
      #pragma unroll
      for (int j = 0; j < 8; ++j) {
        const int it = ks * 32 + quad * 8 + j;
        treg[mt][ks * 8 + j] = (it == 0) ? 1.0f : text[m * 128 + it - 1];
      }
  }

  f32x4 acc[2][8];
  #pragma unroll
  for (int a = 0; a < 2; ++a)
    #pragma unroll
    for (int b = 0; b < 8; ++b) acc[a][b] = f32x4{0.f, 0.f, 0.f, 0.f};

  float pfA[32], pfB[32], rv[8];

  for (int c0 = 0; c0 < np; c0 += CHUNK) {
    const int nc = (np - c0) < CHUNK ? (np - c0) : CHUNK;
    const int pbase = p0 + c0;
    __syncthreads();   // prev chunk fully done (av_lds + b_lds reusable)
    if (tid < BATCH) {
      const int m = tid;
      for (int j = 0; j < nc; ++j) {
        int p = pbase + j;
        int ia = p / 33, iv = p - ia * 33;
        float a = (ia == 0) ? 1.0f : audio[m * 32 + ia - 1];
        float v = (iv == 0) ? 1.0f : video[m * 32 + iv - 1];
        av_lds[m * CHUNK + j] = a * v;
      }
    }
    // remainder row (it=128) — oldest in-flight loads, always drained first
    #pragma unroll
    for (int j = 0; j < 8; ++j) {
      int kk = skg * 8 + j;
      rv[j] = (kk < nc) ? W1[((long)(pbase + kk) * T1 + 128) * PFD + sn] : 0.0f;
    }
    // prime depth-2: pair 0 -> pfA, pair 1 -> pfB
    {
      const long rbA = (long)pbase * T1;
      #pragma unroll
      for (int g = 0; g < 4; ++g)
        #pragma unroll
        for (int j = 0; j < 8; ++j)
          pfA[g * 8 + j] = W1[(rbA + g * 32 + skg * 8 + j) * PFD + sn];
    }
    {
      const long rbB = (long)(pbase + (nc > 1 ? 1 : 0)) * T1;
      #pragma unroll
      for (int g = 0; g < 4; ++g)
        #pragma unroll
        for (int j = 0; j < 8; ++j)
          pfB[g * 8 + j] = W1[(rbB + g * 32 + skg * 8 + j) * PFD + sn];
    }

    for (int sp = 0; sp < nc; sp += 2) {
      // ======== pair sp : pfA -> buf 0 ========
      {
        union { bf16x8 v; unsigned u[4]; } w;
        #pragma unroll
        for (int g = 0; g < 4; ++g) {
          #pragma unroll
          for (int d = 0; d < 4; ++d)
            w.u[d] = pk_bf16(pfA[g * 8 + 2 * d], pfA[g * 8 + 2 * d + 1]);
          *(bf16x8*)&b_lds[0][sn * BK2 + g * 32 + skg * 8] = w.v;
        }
      }
      __syncthreads();   // buf0 staged; drain cheap (pfA consumed)
      if (sp + 2 < nc) {   // refill pfA with pair sp+2 (2 phases of cover)
        const long rb = (long)(pbase + sp + 2) * T1;
        #pragma unroll
        for (int g = 0; g < 4; ++g)
          #pragma unroll
          for (int j = 0; j < 8; ++j)
            pfA[g * 8 + j] = W1[(rb + g * 32 + skg * 8 + j) * PFD + sn];
      }
      {
        const float avm0 = av_lds[(wave * 32 + l15) * CHUNK + sp];
        const float avm1 = av_lds[(wave * 32 + 16 + l15) * CHUNK + sp];
        #pragma unroll
        for (int ks = 0; ks < 4; ++ks) {
          bf16x8 A0, A1;
          {
            union { bf16x8 v; unsigned u[4]; } c0u, c1u;
            #pragma unroll
            for (int d = 0; d < 4; ++d) {
              c0u.u[d] = pk_bf16(avm0 * treg[0][ks * 8 + 2 * d], avm0 * treg[0][ks * 8 + 2 * d + 1]);
              c1u.u[d] = pk_bf16(avm1 * treg[1][ks * 8 + 2 * d], avm1 * treg[1][ks * 8 + 2 * d + 1]);
            }
            A0 = c0u.v; A1 = c1u.v;
          }
          #pragma unroll
          for (int nt = 0; nt < 8; ++nt) {
            bf16x8 bf = *(const bf16x8*)&b_lds[0][(nt * 16 + l15) * BK2 + ks * 32 + quad * 8];
            acc[0][nt] = __builtin_amdgcn_mfma_f32_16x16x32_bf16(A0, bf, acc[0][nt], 0, 0, 0);
            acc[1][nt] = __builtin_amdgcn_mfma_f32_16x16x32_bf16(A1, bf, acc[1][nt], 0, 0, 0);
          }
        }
      }
      if (sp + 1 >= nc) break;   // nc is block-uniform
      // ======== pair sp+1 : pfB -> buf 1 ========
      {
        union { bf16x8 v; unsigned u[4]; } w;
        #pragma unroll
        for (int g = 0; g < 4; ++g) {
          #pragma unroll
          for (int d = 0; d < 4; ++d)
            w.u[d] = pk_bf16(pfB[g * 8 + 2 * d], pfB[g * 8 + 2 * d + 1]);
          *(bf16x8*)&b_lds[1][sn * BK2 + g * 32 + skg * 8] = w.v;
        }
      }
      __syncthreads();   // buf1 staged
      if (sp + 3 < nc) {   // refill pfB with pair sp+3
        const long rb = (long)(pbase + sp + 3) * T1;
        #pragma unroll
        for (int g = 0; g < 4; ++g)
          #pragma unroll
          for (int j = 0; j < 8; ++j)
            pfB[g * 8 + j] = W1[(rb + g * 32 + skg * 8 + j) * PFD + sn];
      }
      {
        const float avm0 = av_lds[(wave * 32 + l15) * CHUNK + sp + 1];
        const float avm1 = av_lds[(wave * 32 + 16 + l15) * CHUNK + sp + 1];
        #pragma unroll
        for (int ks = 0; ks < 4; ++ks) {
          bf16x8 A0, A1;
          {
            union { bf16x8 v; unsigned u[4]; } c0u, c1u;
            #pragma unroll
            for (int d = 0; d < 4; ++d) {
              c0u.u[d] = pk_bf16(avm0 * treg[0][ks * 8 + 2 * d], avm0 * treg[0][ks * 8 + 2 * d + 1]);
              c1u.u[d] = pk_bf16(avm1 * treg[1][ks * 8 + 2 * d], avm1 * treg[1][ks * 8 + 2 * d + 1]);
            }
            A0 = c0u.v; A1 = c1u.v;
          }
          #pragma unroll
          for (int nt = 0; nt < 8; ++nt) {
            bf16x8 bf = *(const bf16x8*)&b_lds[1][(nt * 16 + l15) * BK2 + ks * 32 + quad * 8];
            acc[0][nt] = __builtin_amdgcn_mfma_f32_16x16x32_bf16(A0, bf, acc[0][nt], 0, 0, 0);
            acc[1][nt] = __builtin_amdgcn_mfma_f32_16x16x32_bf16(A1, bf, acc[1][nt], 0, 0, 0);
          }
        }
      }
    }

    // ---- remainder tile: it=128, k-slot = pair index within chunk ----
    __syncthreads();   // all compute done; b_lds[0] reusable
    {
      union { bf16x8 v; unsigned u[4]; } w;
      #pragma unroll
      for (int d = 0; d < 4; ++d) w.u[d] = pk_bf16(rv[2 * d], rv[2 * d + 1]);
      *(bf16x8*)&b_lds[0][sn * BK2 + skg * 8] = w.v;
    }
    __syncthreads();
    {
      bf16x8 A[2];
      #pragma unroll
      for (int mt = 0; mt < 2; ++mt) {
        const int m = wave * 32 + mt * 16 + l15;
        union { bf16x8 v; unsigned u[4]; } c;
        #pragma unroll
        for (int d = 0; d < 4; ++d) {
          int k0 = quad * 8 + 2 * d, k1 = k0 + 1;
          float f0 = (k0 < nc) ? av_lds[m * CHUNK + k0] * t128r[mt] : 0.0f;
          float f1 = (k1 < nc) ? av_lds[m * CHUNK + k1] * t128r[mt] : 0.0f;
          c.u[d] = pk_bf16(f0, f1);
        }
        A[mt] = c.v;
      }
      #pragma unroll
      for (int nt = 0; nt < 8; ++nt) {
        bf16x8 bf = *(const bf16x8*)&b_lds[0][(nt * 16 + l15) * BK2 + quad * 8];
        acc[0][nt] = __builtin_amdgcn_mfma_f32_16x16x32_bf16(A[0], bf, acc[0][nt], 0, 0, 0);
        acc[1][nt] = __builtin_amdgcn_mfma_f32_16x16x32_bf16(A[1], bf, acc[1][nt], 0, 0, 0);
      }
    }
  }

  // writeback: bf16, m-major [m][S][phys_n], phys n = l15*8 + nt
  #pragma unroll
  for (int mt = 0; mt < 2; ++mt)
    #pragma unroll
    for (int r = 0; r < 4; ++r) {
      const int m = wave * 32 + mt * 16 + quad * 4 + r;
      union { bf16x8 v; unsigned u[4]; } w;
      #pragma unroll
      for (int d = 0; d < 4; ++d) w.u[d] = pk_bf16(acc[mt][2 * d][r], acc[mt][2 * d + 1][r]);
      *(bf16x8*)&part[((size_t)m * S + bk) * PFD + l15 * 8] = w.v;
    }
}

// ---------------- Kernel 2: contiguous reduce + bias/relu + layers 2,3 ----------------
__global__ __launch_bounds__(1024) void tfn_k2(
    const unsigned short* __restrict__ part, const float* __restrict__ b1,
    const float* __restrict__ W2, const float* __restrict__ b2,
    const float* __restrict__ W3, const float* __restrict__ b3,
    float* __restrict__ out, int S) {
  __shared__ float sred[1024 * 4];   // 16 KB
  __shared__ float h1s[PFD];
  __shared__ float a2s[1024];
  __shared__ float red[2];
  const int m = blockIdx.x, tid = threadIdx.x;
  const int g = tid & 31, q = tid >> 5;       // 32 s-groups of 32 slabs
  const unsigned short* base = part + (size_t)m * S * PFD;
  float s0 = 0, s1 = 0, s2 = 0, s3 = 0;
  for (int bkk = q; bkk < S; bkk += 32) {
    uint2 v = *(const uint2*)&base[(size_t)bkk * PFD + g * 4];
    s0 += float_of(v.x << 16);
    s1 += float_of(v.x & 0xFFFF0000u);
    s2 += float_of(v.y << 16);
    s3 += float_of(v.y & 0xFFFF0000u);
  }
  sred[tid * 4 + 0] = s0; sred[tid * 4 + 1] = s1;
  sred[tid * 4 + 2] = s2; sred[tid * 4 + 3] = s3;
  __syncthreads();
  if (tid < PFD) {
    const int p = tid;
    float h = 0;
    #pragma unroll
    for (int bl = 0; bl < 32; ++bl) h += sred[(bl * 32 + (p >> 2)) * 4 + (p & 3)];
    const int n = (p & 7) * 16 + (p >> 3);   // un-swizzle phys -> logical
    h1s[n] = fmaxf(h + b1[n], 0.0f);
  }
  __syncthreads();
  const int n = tid & 127, kq = tid >> 7;    // 8 k-groups of 16
  float a2 = 0.0f;
  const int k0 = kq * 16;
  #pragma unroll
  for (int k = 0; k < 16; ++k) a2 += h1s[k0 + k] * W2[(k0 + k) * PFD + n];
  a2s[tid] = a2;
  __syncthreads();
  if (tid < 128) {
    float h2 = 0.0f;
    #pragma unroll
    for (int j = 0; j < 8; ++j) h2 += a2s[n + 128 * j];
    h2 = fmaxf(h2 + b2[n], 0.0f);
    float pr = h2 * W3[n];
    #pragma unroll
    for (int off = 32; off > 0; off >>= 1) pr += __shfl_down(pr, off);
    if ((tid & 63) == 0) red[tid >> 6] = pr;
  }
  __syncthreads();
  if (tid == 0) out[m] = red[0] + red[1] + b3[0];
}

extern "C" void kernel_launch(void* const* d_in, const int* in_sizes, int n_in,
                              void* d_out, int out_size, void* d_ws, size_t ws_size,
                              hipStream_t stream) {
  const float* audio = (const float*)d_in[0];
  const float* video = (const float*)d_in[1];
  const float* text  = (const float*)d_in[2];
  const float* W1 = (const float*)d_in[3];
  const float* b1 = (const float*)d_in[4];
  const float* W2 = (const float*)d_in[5];
  const float* b2 = (const float*)d_in[6];
  const float* W3 = (const float*)d_in[7];
  const float* b3 = (const float*)d_in[8];
  unsigned short* part = (unsigned short*)d_ws;

  const size_t slab = (size_t)BATCH * PFD * sizeof(unsigned short);  // 64 KB
  int S = (int)(ws_size / slab);
  if (S > 256) S = 256;   // 1 block/CU forced by regs; one round, min fixed overhead
  if (S < 1) S = 1;

  tfn_k1<<<S, 512, 0, stream>>>(audio, video, text, W1, part, S);
  tfn_k2<<<BATCH, 1024, 0, stream>>>(part, b1, W2, b2, W3, b3, (float*)d_out, S);
}

// Round 11
// 135.697 us; speedup vs baseline: 1.2912x; 1.0803x over previous
//
#include <hip/hip_runtime.h>
#include <hip/hip_bf16.h>
#include <stdint.h>

#define BATCH 256
#define PFD 128
#define T1 129
#define NPAIRS 1089      // 33*33
#define BK2 136          // b_lds row stride (shorts): 128 k + 8 pad; 68 dw = 4 mod 32 banks
#define CHUNK 8

typedef short bf16x8 __attribute__((ext_vector_type(8)));
typedef float f32x4 __attribute__((ext_vector_type(4)));

static __device__ __forceinline__ float float_of(unsigned u){ union{float f;unsigned u;}x;x.u=u;return x.f; }
static __device__ __forceinline__ unsigned pk_bf16(float a, float b){
  union { __hip_bfloat162 h; unsigned u; } c;
  c.h = __float22bfloat162_rn(make_float2(a, b));
  return c.u;
}

// ---------------- Kernel 1: split-K fused trilinear GEMM ----------------
// FINAL (session best, 136.2us total, measured round 3; round-10 bench was an
// infra failure so this is an unchanged resubmission). 1 block/CU is forced
// (128 VGPR + 64 AGPR = ~192 regs/wave -> 2 waves/SIMD), so all latency
// hiding is intra-block. Structure per pair sp:
//   staging:  pk(pf) -> 4x ds_write_b128 into b_lds[sp&1]   (pf loaded last sp)
//   barrier   (the vmcnt(0) drain is FREE: pf was already consumed by pk)
//   compute:  issue 32 W1 loads for sp+1 (in flight under compute),
//             4 ks x { A-frag pk; 8 nt x 2 MFMA }  (32 ds_read_b128)
// ONE barrier per pair. Correctness of single barrier with 2-deep buffer:
// reads of buf[sp&1] lie between barrier(sp) and that wave's staging(sp+1)
// (program order); the next write to buf[sp&1] is staging(sp+2), which follows
// barrier(sp+1), which follows ALL waves' staging(sp+1), which follows each
// wave's compute(sp). So no write can overlap a read.
// Toolchain constraints learned rounds 1,4-9 (all counter-verified failures):
// - 256-thread blocks: allocator clamps to 80 VGPR + spills (any bounds).
// - __launch_bounds__ min-waves > 2: clamps to 64 VGPR + 175MB spill.
// - inline-asm s_waitcnt / sched_barrier(0): conservative drains or spills.
// - global_load_lds DMA staging: neutral (supply width not the limiter).
// - depth-2 register prefetch: +32 regs -> pressure regression (47us).
__global__ __launch_bounds__(512, 2) void tfn_k1(
    const float* __restrict__ audio, const float* __restrict__ video,
    const float* __restrict__ text, const float* __restrict__ W1,
    unsigned short* __restrict__ part, int S) {
  __shared__ __align__(16) short b_lds[2][PFD * BK2];   // 2 x 34816 B
  __shared__ __align__(16) float av_lds[BATCH * CHUNK]; // 8192 B

  const int tid = threadIdx.x;
  const int bk = blockIdx.x;
  const int npb = NPAIRS / S, rem0 = NPAIRS % S;
  const int p0 = bk * npb + (bk < rem0 ? bk : rem0);
  const int np = npb + (bk < rem0 ? 1 : 0);

  const int wave = tid >> 6, lane = tid & 63;
  const int l15 = lane & 15, quad = lane >> 4;
  const int sn = tid & 127, skg = tid >> 7;

  // t fragments in registers, fp32, MFMA A-layout: treg[mt][ks*8+j] = t(m, ks*32+quad*8+j)
  float treg[2][32];
  float t128r[2];
  #pragma unroll
  for (int mt = 0; mt < 2; ++mt) {
    const int m = wave * 32 + mt * 16 + l15;
    t128r[mt] = text[m * 128 + 127];
    #pragma unroll
    for (int ks = 0; ks < 4; ++ks)
      #pragma unroll
      for (int j = 0; j < 8; ++j) {
        const int it = ks * 32 + quad * 8 + j;
        treg[mt][ks * 8 + j] = (it == 0) ? 1.0f : text[m * 128 + it - 1];
      }
  }

  f32x4 acc[2][8];
  #pragma unroll
  for (int a = 0; a < 2; ++a)
    #pragma unroll
    for (int b = 0; b < 8; ++b) acc[a][b] = f32x4{0.f, 0.f, 0.f, 0.f};

  float pf[32], rv[8];

  for (int c0 = 0; c0 < np; c0 += CHUNK) {
    const int nc = (np - c0) < CHUNK ? (np - c0) : CHUNK;
    const int pbase = p0 + c0;
    __syncthreads();   // prev chunk fully done (av_lds + b_lds[0] reusable)
    if (tid < BATCH) {
      const int m = tid;
      for (int j = 0; j < nc; ++j) {
        int p = pbase + j;
        int ia = p / 33, iv = p - ia * 33;
        float a = (ia == 0) ? 1.0f : audio[m * 32 + ia - 1];
        float v = (iv == 0) ? 1.0f : video[m * 32 + iv - 1];
        av_lds[m * CHUNK + j] = a * v;
      }
    }
    // remainder row (it=128) — in flight across whole chunk
    #pragma unroll
    for (int j = 0; j < 8; ++j) {
      int kk = skg * 8 + j;
      rv[j] = (kk < nc) ? W1[((long)(pbase + kk) * T1 + 128) * PFD + sn] : 0.0f;
    }
    // prime: loads for sp=0 (full pair, 128 k rows; thread covers k = g*32+skg*8+j)
    {
      const long rb = (long)pbase * T1;
      #pragma unroll
      for (int g = 0; g < 4; ++g)
        #pragma unroll
        for (int j = 0; j < 8; ++j)
          pf[g * 8 + j] = W1[(rb + g * 32 + skg * 8 + j) * PFD + sn];
    }
    for (int sp = 0; sp < nc; ++sp) {
      // ---- staging: pf (pair sp) -> b_lds[sp&1]; vmcnt wait happens at pk ----
      {
        union { bf16x8 v; unsigned u[4]; } w;
        #pragma unroll
        for (int g = 0; g < 4; ++g) {
          #pragma unroll
          for (int d = 0; d < 4; ++d)
            w.u[d] = pk_bf16(pf[g * 8 + 2 * d], pf[g * 8 + 2 * d + 1]);
          *(bf16x8*)&b_lds[sp & 1][sn * BK2 + g * 32 + skg * 8] = w.v;
        }
      }
      __syncthreads();   // buf[sp&1] staged; drain is cheap (pf already consumed)
      // ---- issue next pair's loads NOW: in flight under the whole compute phase ----
      if (sp + 1 < nc) {
        const long rb = (long)(pbase + sp + 1) * T1;
        #pragma unroll
        for (int g = 0; g < 4; ++g)
          #pragma unroll
          for (int j = 0; j < 8; ++j)
            pf[g * 8 + j] = W1[(rb + g * 32 + skg * 8 + j) * PFD + sn];
      }
      // ---- compute pair sp ----
      const float avm0 = av_lds[(wave * 32 + l15) * CHUNK + sp];
      const float avm1 = av_lds[(wave * 32 + 16 + l15) * CHUNK + sp];
      #pragma unroll
      for (int ks = 0; ks < 4; ++ks) {
        bf16x8 A0, A1;
        {
          union { bf16x8 v; unsigned u[4]; } c0u, c1u;
          #pragma unroll
          for (int d = 0; d < 4; ++d) {
            c0u.u[d] = pk_bf16(avm0 * treg[0][ks * 8 + 2 * d], avm0 * treg[0][ks * 8 + 2 * d + 1]);
            c1u.u[d] = pk_bf16(avm1 * treg[1][ks * 8 + 2 * d], avm1 * treg[1][ks * 8 + 2 * d + 1]);
          }
          A0 = c0u.v; A1 = c1u.v;
        }
        #pragma unroll
        for (int nt = 0; nt < 8; ++nt) {
          bf16x8 bf = *(const bf16x8*)&b_lds[sp & 1][(nt * 16 + l15) * BK2 + ks * 32 + quad * 8];
          acc[0][nt] = __builtin_amdgcn_mfma_f32_16x16x32_bf16(A0, bf, acc[0][nt], 0, 0, 0);
          acc[1][nt] = __builtin_amdgcn_mfma_f32_16x16x32_bf16(A1, bf, acc[1][nt], 0, 0, 0);
        }
      }
    }
    // ---- remainder tile: it=128, k-slot = pair index within chunk ----
    __syncthreads();
    {
      union { bf16x8 v; unsigned u[4]; } w;
      #pragma unroll
      for (int d = 0; d < 4; ++d) w.u[d] = pk_bf16(rv[2 * d], rv[2 * d + 1]);
      *(bf16x8*)&b_lds[0][sn * BK2 + skg * 8] = w.v;
    }
    __syncthreads();
    {
      bf16x8 A[2];
      #pragma unroll
      for (int mt = 0; mt < 2; ++mt) {
        const int m = wave * 32 + mt * 16 + l15;
        union { bf16x8 v; unsigned u[4]; } c;
        #pragma unroll
        for (int d = 0; d < 4; ++d) {
          int k0 = quad * 8 + 2 * d, k1 = k0 + 1;
          float f0 = (k0 < nc) ? av_lds[m * CHUNK + k0] * t128r[mt] : 0.0f;
          float f1 = (k1 < nc) ? av_lds[m * CHUNK + k1] * t128r[mt] : 0.0f;
          c.u[d] = pk_bf16(f0, f1);
        }
        A[mt] = c.v;
      }
      #pragma unroll
      for (int nt = 0; nt < 8; ++nt) {
        bf16x8 bf = *(const bf16x8*)&b_lds[0][(nt * 16 + l15) * BK2 + quad * 8];
        acc[0][nt] = __builtin_amdgcn_mfma_f32_16x16x32_bf16(A[0], bf, acc[0][nt], 0, 0, 0);
        acc[1][nt] = __builtin_amdgcn_mfma_f32_16x16x32_bf16(A[1], bf, acc[1][nt], 0, 0, 0);
      }
    }
  }

  // writeback: bf16, m-major [m][S][phys_n], phys n = l15*8 + nt
  #pragma unroll
  for (int mt = 0; mt < 2; ++mt)
    #pragma unroll
    for (int r = 0; r < 4; ++r) {
      const int m = wave * 32 + mt * 16 + quad * 4 + r;
      union { bf16x8 v; unsigned u[4]; } w;
      #pragma unroll
      for (int d = 0; d < 4; ++d) w.u[d] = pk_bf16(acc[mt][2 * d][r], acc[mt][2 * d + 1][r]);
      *(bf16x8*)&part[((size_t)m * S + bk) * PFD + l15 * 8] = w.v;
    }
}

// ---------------- Kernel 2: contiguous reduce + bias/relu + layers 2,3 ----------------
// 1024 threads (16 waves/CU): S-slab reduction split 32-way, W2 layer split
// 8-way over k.
__global__ __launch_bounds__(1024) void tfn_k2(
    const unsigned short* __restrict__ part, const float* __restrict__ b1,
    const float* __restrict__ W2, const float* __restrict__ b2,
    const float* __restrict__ W3, const float* __restrict__ b3,
    float* __restrict__ out, int S) {
  __shared__ float sred[1024 * 4];   // 16 KB
  __shared__ float h1s[PFD];
  __shared__ float a2s[1024];
  __shared__ float red[2];
  const int m = blockIdx.x, tid = threadIdx.x;
  const int g = tid & 31, q = tid >> 5;       // 32 s-groups of 32 slabs
  const unsigned short* base = part + (size_t)m * S * PFD;
  float s0 = 0, s1 = 0, s2 = 0, s3 = 0;
  for (int bkk = q; bkk < S; bkk += 32) {
    uint2 v = *(const uint2*)&base[(size_t)bkk * PFD + g * 4];
    s0 += float_of(v.x << 16);
    s1 += float_of(v.x & 0xFFFF0000u);
    s2 += float_of(v.y << 16);
    s3 += float_of(v.y & 0xFFFF0000u);
  }
  sred[tid * 4 + 0] = s0; sred[tid * 4 + 1] = s1;
  sred[tid * 4 + 2] = s2; sred[tid * 4 + 3] = s3;
  __syncthreads();
  if (tid < PFD) {
    const int p = tid;
    float h = 0;
    #pragma unroll
    for (int bl = 0; bl < 32; ++bl) h += sred[(bl * 32 + (p >> 2)) * 4 + (p & 3)];
    const int n = (p & 7) * 16 + (p >> 3);   // un-swizzle phys -> logical
    h1s[n] = fmaxf(h + b1[n], 0.0f);
  }
  __syncthreads();
  const int n = tid & 127, kq = tid >> 7;    // 8 k-groups of 16
  float a2 = 0.0f;
  const int k0 = kq * 16;
  #pragma unroll
  for (int k = 0; k < 16; ++k) a2 += h1s[k0 + k] * W2[(k0 + k) * PFD + n];
  a2s[tid] = a2;
  __syncthreads();
  if (tid < 128) {
    float h2 = 0.0f;
    #pragma unroll
    for (int j = 0; j < 8; ++j) h2 += a2s[n + 128 * j];
    h2 = fmaxf(h2 + b2[n], 0.0f);
    float pr = h2 * W3[n];
    #pragma unroll
    for (int off = 32; off > 0; off >>= 1) pr += __shfl_down(pr, off);
    if ((tid & 63) == 0) red[tid >> 6] = pr;
  }
  __syncthreads();
  if (tid == 0) out[m] = red[0] + red[1] + b3[0];
}

extern "C" void kernel_launch(void* const* d_in, const int* in_sizes, int n_in,
                              void* d_out, int out_size, void* d_ws, size_t ws_size,
                              hipStream_t stream) {
  const float* audio = (const float*)d_in[0];
  const float* video = (const float*)d_in[1];
  const float* text  = (const float*)d_in[2];
  const float* W1 = (const float*)d_in[3];
  const float* b1 = (const float*)d_in[4];
  const float* W2 = (const float*)d_in[5];
  const float* b2 = (const float*)d_in[6];
  const float* W3 = (const float*)d_in[7];
  const float* b3 = (const float*)d_in[8];
  unsigned short* part = (unsigned short*)d_ws;

  const size_t slab = (size_t)BATCH * PFD * sizeof(unsigned short);  // 64 KB
  int S = (int)(ws_size / slab);
  if (S > 256) S = 256;   // 1 block/CU is forced by regs; one round, min fixed overhead
  if (S < 1) S = 1;

  tfn_k1<<<S, 512, 0, stream>>>(audio, video, text, W1, part, S);
  tfn_k2<<<BATCH, 1024, 0, stream>>>(part, b1, W2, b2, W3, b3, (float*)d_out, S);
}